// Round 3
// baseline (1093.640 us; speedup 1.0000x reference)
//
#include <hip/hip_runtime.h>
#include <hip/hip_bf16.h>

#define T_STEPS 2048
#define BATCH   256
#define DIM     128

#define ZX_FLOATS (T_STEPS * BATCH * 16)   // 33,554,432 floats

// ---------------------------------------------------------------------------
// prep: pack weights Wc[d*16 + (g*4+k)] = W_g[d*4+k], bt[u] = b_g[k]+theta_g[k]
// ---------------------------------------------------------------------------
__global__ __launch_bounds__(64) void prep(
    const float* __restrict__ Wf, const float* __restrict__ bf, const float* __restrict__ tf,
    const float* __restrict__ Wi, const float* __restrict__ bi, const float* __restrict__ ti,
    const float* __restrict__ Wu, const float* __restrict__ bu, const float* __restrict__ tu,
    const float* __restrict__ Wo, const float* __restrict__ bo, const float* __restrict__ to_,
    float* __restrict__ Wc, float* __restrict__ bt)
{
    const int tid = threadIdx.x;
    for (int idx = tid; idx < DIM * 16; idx += 64) {
        int d = idx >> 4, u = idx & 15, g = u >> 2, k = u & 3;
        const float* W = (g == 0) ? Wf : (g == 1) ? Wi : (g == 2) ? Wu : Wo;
        Wc[idx] = W[d * 4 + k];
    }
    if (tid < 16) {
        int g = tid >> 2, k = tid & 3;
        const float* bb = (g == 0) ? bf : (g == 1) ? bi : (g == 2) ? bu : bo;
        const float* tt = (g == 0) ? tf : (g == 1) ? ti : (g == 2) ? tu : to_;
        bt[tid] = bb[k] + tt[k];
    }
}

// ---------------------------------------------------------------------------
// Kernel 1 v2: coalesced LDS-staged skinny GEMM.
// Block = 1 wave = 64 rows. x tile staged coalesced into LDS (pad 132 floats,
// 16B-aligned rows). Weights read with wave-uniform indices -> scalar loads.
// ---------------------------------------------------------------------------
__global__ __launch_bounds__(64) void zx_gemm(
    const float4* __restrict__ x4,
    const float*  __restrict__ Wc,    // [128][16] packed
    const float*  __restrict__ btv,   // [16]
    float4*       __restrict__ Zx4)
{
    __shared__ float xs[64 * 132];    // 33792 B
    const int lane = threadIdx.x;
    const size_t tile = blockIdx.x;            // 64 rows per tile
    const size_t base4 = tile * (64 * 32);     // float4 index of tile start

#pragma unroll
    for (int i = 0; i < 32; ++i) {
        int idx = i * 64 + lane;
        float4 v = x4[base4 + idx];
        int r = idx >> 5, c = idx & 31;
        *(float4*)&xs[r * 132 + c * 4] = v;    // 132*4B row stride: 16B aligned
    }
    __syncthreads();

    float acc[16];
#pragma unroll
    for (int u = 0; u < 16; ++u) acc[u] = btv[u];   // uniform -> scalar loads

    const float* xr = &xs[lane * 132];
#pragma unroll 4
    for (int d4 = 0; d4 < 32; ++d4) {
        float4 xv = *(const float4*)&xr[d4 * 4];
        const float* w = &Wc[d4 * 64];          // uniform -> s_load
#pragma unroll
        for (int u = 0; u < 16; ++u) acc[u] = fmaf(xv.x, w[u],      acc[u]);
#pragma unroll
        for (int u = 0; u < 16; ++u) acc[u] = fmaf(xv.y, w[16 + u], acc[u]);
#pragma unroll
        for (int u = 0; u < 16; ++u) acc[u] = fmaf(xv.z, w[32 + u], acc[u]);
#pragma unroll
        for (int u = 0; u < 16; ++u) acc[u] = fmaf(xv.w, w[48 + u], acc[u]);
    }

    size_t orow = tile * 64 + lane;
    float4* zr = &Zx4[orow * 4];
    zr[0] = make_float4(acc[0],  acc[1],  acc[2],  acc[3]);
    zr[1] = make_float4(acc[4],  acc[5],  acc[6],  acc[7]);
    zr[2] = make_float4(acc[8],  acc[9],  acc[10], acc[11]);
    zr[3] = make_float4(acc[12], acc[13], acc[14], acc[15]);
}

// ---------------------------------------------------------------------------
// Kernel 2 v2: recurrence with DPP cross-lane (no LDS-path latency) and
// 2-way batch-group interleave per wave for ILP.
// Lane u = g*4+k within each 16-lane row; 4 rows per wave.
// ---------------------------------------------------------------------------
template<int CTRL>
__device__ __forceinline__ float fdpp(float x) {
    return __int_as_float(__builtin_amdgcn_update_dpp(
        0, __float_as_int(x), CTRL, 0xF, 0xF, true));
}

// quad_perm broadcasts: 0x00,0x55,0xAA,0xFF ; quad mirror [3,2,1,0] = 0x1B
// row_half_mirror = 0x141 ; row_ror:8 = 0x128
__device__ __forceinline__ float lstm_step(
    float& h, float& c, float zb,
    float wh0, float wh1, float wh2, float wh3,
    float s1c, float m2, float m3, int k, bool b0g, bool b1g)
{
    // h-gather (intra-quad: lane g*4+j holds h_j)
    float h0 = fdpp<0x00>(h), h1 = fdpp<0x55>(h), h2 = fdpp<0xAA>(h), h3 = fdpp<0xFF>(h);
    float t1 = fmaf(h2, wh2, h3 * wh3);
    float z  = fmaf(h1, wh1, fmaf(h0, wh0, zb)) + t1;

    float cs = __builtin_amdgcn_cosf(__builtin_amdgcn_fractf(z * 0.15915494309f));

    // cumprod over k within quad
    float q0 = fdpp<0x00>(cs), q1 = fdpp<0x55>(cs), q2 = fdpp<0xAA>(cs);
    float p = (q0 * (k >= 1 ? q1 : 1.f)) * ((k >= 2 ? q2 : 1.f) * (k == 3 ? cs : 1.f));

    // activation: sigmoid (f,i,o) or tanh (update)
    float e = __builtin_amdgcn_exp2f(p * s1c);
    float y = fmaf(__builtin_amdgcn_rcpf(1.f + e), m2, m3);

    // gate exchange: y4 = xor4 (quad-mirror then half-mirror), y8 = xor8, y12 = xor12
    float mm  = fdpp<0x1B>(y);
    float y4  = fdpp<0x141>(mm);
    float y8  = fdpp<0x128>(y);
    float y12 = fdpp<0x128>(y4);
    float t01  = b0g ? y4  : y,  t01s = b0g ? y  : y4;
    float t23  = b0g ? y12 : y8, t23s = b0g ? y8 : y12;
    float fv = b1g ? t23  : t01;
    float iv = b1g ? t23s : t01s;
    float gv = b1g ? t01  : t23;
    float ov = b1g ? t01s : t23s;

    c = fmaf(fv, c, iv * gv);
    float e2 = __builtin_amdgcn_exp2f(c * -2.885390082f);
    float th = fmaf(2.f, __builtin_amdgcn_rcpf(1.f + e2), -1.f);
    h = ov * th;
    return h;
}

__global__ __launch_bounds__(64) void qlstm_rec(
    const float* __restrict__ Zx,
    const float* __restrict__ Wf, const float* __restrict__ Wi,
    const float* __restrict__ Wu, const float* __restrict__ Wo,
    float* __restrict__ out)
{
    const int tid = threadIdx.x;
    const int u   = tid & 15;
    const int g   = u >> 2;
    const int k   = u & 3;
    const int bA  = blockIdx.x * 8 + (tid >> 4);
    const int bB  = bA + 4;

    const float* Wg = (g == 0) ? Wf : (g == 1) ? Wi : (g == 2) ? Wu : Wo;
    const float wh0 = Wg[(DIM + 0) * 4 + k];
    const float wh1 = Wg[(DIM + 1) * 4 + k];
    const float wh2 = Wg[(DIM + 2) * 4 + k];
    const float wh3 = Wg[(DIM + 3) * 4 + k];

    const bool  isg = (g == 2);
    const float s1c = isg ? -2.885390082f : -1.442695041f;
    const float m2  = isg ? 2.f : 1.f;
    const float m3  = isg ? -1.f : 0.f;
    const bool  b0g = (g & 1) != 0;
    const bool  b1g = (g & 2) != 0;

    const float* zpA = Zx + bA * 16 + u;    // step stride B*16 = 4096
    const float* zpB = Zx + bB * 16 + u;
    const bool do_store = (u < 4);
    float* opA = out + bA * 4 + k;
    float* opB = out + bB * 4 + k;

    float hA = 0.f, cA = 0.f, hB = 0.f, cB = 0.f;

    float zA[8], zB[8];
#pragma unroll
    for (int i = 0; i < 8; ++i) {
        zA[i] = zpA[(size_t)i * 4096];
        zB[i] = zpB[(size_t)i * 4096];
    }

    for (int t = 0; t < T_STEPS; ++t) {
        int tn = (t + 8 < T_STEPS) ? t + 8 : T_STEPS - 1;
        float znA = zpA[(size_t)tn * 4096];
        float znB = zpB[(size_t)tn * 4096];

        float oA = lstm_step(hA, cA, zA[0], wh0, wh1, wh2, wh3, s1c, m2, m3, k, b0g, b1g);
        float oB = lstm_step(hB, cB, zB[0], wh0, wh1, wh2, wh3, s1c, m2, m3, k, b0g, b1g);

        if (do_store) {
            opA[(size_t)t * (BATCH * 4)] = oA;
            opB[(size_t)t * (BATCH * 4)] = oB;
        }

#pragma unroll
        for (int i = 0; i < 7; ++i) { zA[i] = zA[i + 1]; zB[i] = zB[i + 1]; }
        zA[7] = znA; zB[7] = znB;
    }

    if (do_store) {
        size_t hx_off = (size_t)T_STEPS * BATCH * 4;
        out[hx_off + bA * 4 + k] = hA;
        out[hx_off + bB * 4 + k] = hB;
        out[hx_off + BATCH * 4 + bA * 4 + k] = cA;
        out[hx_off + BATCH * 4 + bB * 4 + k] = cB;
    }
}

extern "C" void kernel_launch(void* const* d_in, const int* in_sizes, int n_in,
                              void* d_out, int out_size, void* d_ws, size_t ws_size,
                              hipStream_t stream) {
    const float* x  = (const float*)d_in[0];
    const float* Wf = (const float*)d_in[1];
    const float* bf = (const float*)d_in[2];
    const float* tf = (const float*)d_in[3];
    const float* Wi = (const float*)d_in[4];
    const float* bi = (const float*)d_in[5];
    const float* ti = (const float*)d_in[6];
    const float* Wu = (const float*)d_in[7];
    const float* bu = (const float*)d_in[8];
    const float* tu = (const float*)d_in[9];
    const float* Wo = (const float*)d_in[10];
    const float* bo = (const float*)d_in[11];
    const float* to_ = (const float*)d_in[12];
    float* out = (float*)d_out;

    float* Zx = (float*)d_ws;                       // 33.55 MB
    float* Wc = Zx + ZX_FLOATS;                     // 8 KB
    float* bt = Wc + DIM * 16;                      // 64 B

    prep<<<1, 64, 0, stream>>>(Wf, bf, tf, Wi, bi, ti, Wu, bu, tu, Wo, bo, to_, Wc, bt);

    zx_gemm<<<(T_STEPS * BATCH) / 64, 64, 0, stream>>>(
        (const float4*)x, Wc, bt, (float4*)Zx);

    qlstm_rec<<<BATCH / 8, 64, 0, stream>>>(Zx, Wf, Wi, Wu, Wo, out);
}

// Round 4
// 863.177 us; speedup vs baseline: 1.2670x; 1.2670x over previous
//
#include <hip/hip_runtime.h>
#include <hip/hip_bf16.h>

#define T_STEPS 2048
#define BATCH   256
#define DIM     128

#define ZX_FLOATS (T_STEPS * BATCH * 16)   // 33,554,432 floats

// ---------------------------------------------------------------------------
// prep: pack weights Wc[d*16 + (g*4+k)] = W_g[d*4+k], bt[u] = b_g[k]+theta_g[k]
// ---------------------------------------------------------------------------
__global__ __launch_bounds__(64) void prep(
    const float* __restrict__ Wf, const float* __restrict__ bf, const float* __restrict__ tf,
    const float* __restrict__ Wi, const float* __restrict__ bi, const float* __restrict__ ti,
    const float* __restrict__ Wu, const float* __restrict__ bu, const float* __restrict__ tu,
    const float* __restrict__ Wo, const float* __restrict__ bo, const float* __restrict__ to_,
    float* __restrict__ Wc, float* __restrict__ bt)
{
    const int tid = threadIdx.x;
    for (int idx = tid; idx < DIM * 16; idx += 64) {
        int d = idx >> 4, u = idx & 15, g = u >> 2, k = u & 3;
        const float* W = (g == 0) ? Wf : (g == 1) ? Wi : (g == 2) ? Wu : Wo;
        Wc[idx] = W[d * 4 + k];
    }
    if (tid < 16) {
        int g = tid >> 2, k = tid & 3;
        const float* bb = (g == 0) ? bf : (g == 1) ? bi : (g == 2) ? bu : bo;
        const float* tt = (g == 0) ? tf : (g == 1) ? ti : (g == 2) ? tu : to_;
        bt[tid] = bb[k] + tt[k];
    }
}

// ---------------------------------------------------------------------------
// Kernel 1 v4: 256-thread block = 4 waves. Each wave owns an INDEPENDENT
// 64-row tile and an 8.25 KB LDS region (no inter-wave barriers). K is
// processed in 4 chunks of 32 so LDS/block = 33792 B -> 4 blocks/CU
// -> 4 waves/SIMD (latency hiding restored vs R3's 1 wave/SIMD).
// Global x loads fully line-utilized; LDS pad-33 conflict-free b32 reads;
// weights via wave-uniform s_load from packed Wc.
// ---------------------------------------------------------------------------
__global__ __launch_bounds__(256) void zx_gemm(
    const float4* __restrict__ x4,
    const float*  __restrict__ Wc,    // [128][16] packed
    const float*  __restrict__ btv,   // [16]
    float4*       __restrict__ Zx4)
{
    __shared__ float xs[4][64 * 33];         // 33792 B total
    const int lane = threadIdx.x & 63;
    const int wid  = threadIdx.x >> 6;
    float* myxs = xs[wid];
    const size_t wrow0 = ((size_t)blockIdx.x * 4 + wid) * 64;

    float acc[16];
#pragma unroll
    for (int u = 0; u < 16; ++u) acc[u] = btv[u];   // uniform -> s_load

    const int r0 = lane >> 3;                 // 0..7
    const int q  = lane & 7;                  // 0..7

#pragma unroll
    for (int c = 0; c < 4; ++c) {
        float4 v[8];
#pragma unroll
        for (int i = 0; i < 8; ++i) {
            int r = i * 8 + r0;
            v[i] = x4[(wrow0 + r) * 32 + c * 8 + q];
        }
#pragma unroll
        for (int i = 0; i < 8; ++i) {
            int r = i * 8 + r0;
            float* p = &myxs[r * 33 + q * 4];
            p[0] = v[i].x; p[1] = v[i].y; p[2] = v[i].z; p[3] = v[i].w;
        }
        // same-wave DS ops execute in order; compiler inserts lgkmcnt waits
#pragma unroll
        for (int dd = 0; dd < 32; ++dd) {
            float xv = myxs[lane * 33 + dd];         // conflict-free (pad 33)
            const float* w = &Wc[(c * 32 + dd) * 16]; // uniform -> s_load
#pragma unroll
            for (int u = 0; u < 16; ++u) acc[u] = fmaf(xv, w[u], acc[u]);
        }
    }

    size_t orow = wrow0 + lane;
    float4* zr = &Zx4[orow * 4];
    zr[0] = make_float4(acc[0],  acc[1],  acc[2],  acc[3]);
    zr[1] = make_float4(acc[4],  acc[5],  acc[6],  acc[7]);
    zr[2] = make_float4(acc[8],  acc[9],  acc[10], acc[11]);
    zr[3] = make_float4(acc[12], acc[13], acc[14], acc[15]);
}

// ---------------------------------------------------------------------------
// Kernel 2 v3: DPP cross-lane + t-loop unrolled by prefetch depth 8 so the
// 16 prefetch slots are distinct registers -> backend emits s_waitcnt
// vmcnt(14)-style waits (oldest only) instead of the R2/R3 vmcnt(0) drain.
// ---------------------------------------------------------------------------
template<int CTRL>
__device__ __forceinline__ float fdpp(float x) {
    return __int_as_float(__builtin_amdgcn_update_dpp(
        0, __float_as_int(x), CTRL, 0xF, 0xF, true));
}

__device__ __forceinline__ float lstm_step(
    float& h, float& c, float zb,
    float wh0, float wh1, float wh2, float wh3,
    float s1c, float m2, float m3, int k, bool b0g, bool b1g)
{
    float h0 = fdpp<0x00>(h), h1 = fdpp<0x55>(h), h2 = fdpp<0xAA>(h), h3 = fdpp<0xFF>(h);
    float t1 = fmaf(h2, wh2, h3 * wh3);
    float z  = fmaf(h1, wh1, fmaf(h0, wh0, zb)) + t1;

    float cs = __builtin_amdgcn_cosf(__builtin_amdgcn_fractf(z * 0.15915494309f));

    float q0 = fdpp<0x00>(cs), q1 = fdpp<0x55>(cs), q2 = fdpp<0xAA>(cs);
    float p = (q0 * (k >= 1 ? q1 : 1.f)) * ((k >= 2 ? q2 : 1.f) * (k == 3 ? cs : 1.f));

    float e = __builtin_amdgcn_exp2f(p * s1c);
    float y = fmaf(__builtin_amdgcn_rcpf(1.f + e), m2, m3);

    float mm  = fdpp<0x1B>(y);
    float y4  = fdpp<0x141>(mm);
    float y8  = fdpp<0x128>(y);
    float y12 = fdpp<0x128>(y4);
    float t01  = b0g ? y4  : y,  t01s = b0g ? y  : y4;
    float t23  = b0g ? y12 : y8, t23s = b0g ? y8 : y12;
    float fv = b1g ? t23  : t01;
    float iv = b1g ? t23s : t01s;
    float gv = b1g ? t01  : t23;
    float ov = b1g ? t01s : t23s;

    c = fmaf(fv, c, iv * gv);
    float e2 = __builtin_amdgcn_exp2f(c * -2.885390082f);
    float th = fmaf(2.f, __builtin_amdgcn_rcpf(1.f + e2), -1.f);
    h = ov * th;
    return h;
}

__global__ __launch_bounds__(64) void qlstm_rec(
    const float* __restrict__ Zx,
    const float* __restrict__ Wf, const float* __restrict__ Wi,
    const float* __restrict__ Wu, const float* __restrict__ Wo,
    float* __restrict__ out)
{
    const int tid = threadIdx.x;
    const int u   = tid & 15;
    const int g   = u >> 2;
    const int k   = u & 3;
    const int bA  = blockIdx.x * 8 + (tid >> 4);
    const int bB  = bA + 4;

    const float* Wg = (g == 0) ? Wf : (g == 1) ? Wi : (g == 2) ? Wu : Wo;
    const float wh0 = Wg[(DIM + 0) * 4 + k];
    const float wh1 = Wg[(DIM + 1) * 4 + k];
    const float wh2 = Wg[(DIM + 2) * 4 + k];
    const float wh3 = Wg[(DIM + 3) * 4 + k];

    const bool  isg = (g == 2);
    const float s1c = isg ? -2.885390082f : -1.442695041f;
    const float m2  = isg ? 2.f : 1.f;
    const float m3  = isg ? -1.f : 0.f;
    const bool  b0g = (g & 1) != 0;
    const bool  b1g = (g & 2) != 0;

    const float* zpA = Zx + bA * 16 + u;    // step stride B*16 = 4096
    const float* zpB = Zx + bB * 16 + u;
    const bool do_store = (u < 4);
    float* opA = out + bA * 4 + k;
    float* opB = out + bB * 4 + k;

    float hA = 0.f, cA = 0.f, hB = 0.f, cB = 0.f;

    float zA[8], zB[8];
#pragma unroll
    for (int i = 0; i < 8; ++i) {
        zA[i] = zpA[(size_t)i * 4096];
        zB[i] = zpB[(size_t)i * 4096];
    }

    for (int t = 0; t < T_STEPS; t += 8) {
#pragma unroll
        for (int j = 0; j < 8; ++j) {
            int tt = t + j;

            float oA = lstm_step(hA, cA, zA[j], wh0, wh1, wh2, wh3, s1c, m2, m3, k, b0g, b1g);
            float oB = lstm_step(hB, cB, zB[j], wh0, wh1, wh2, wh3, s1c, m2, m3, k, b0g, b1g);

            if (do_store) {
                opA[(size_t)tt * (BATCH * 4)] = oA;
                opB[(size_t)tt * (BATCH * 4)] = oB;
            }

            int tn = tt + 8;
            if (tn > T_STEPS - 1) tn = T_STEPS - 1;
            zA[j] = zpA[(size_t)tn * 4096];
            zB[j] = zpB[(size_t)tn * 4096];
        }
    }

    if (do_store) {
        size_t hx_off = (size_t)T_STEPS * BATCH * 4;
        out[hx_off + bA * 4 + k] = hA;
        out[hx_off + bB * 4 + k] = hB;
        out[hx_off + BATCH * 4 + bA * 4 + k] = cA;
        out[hx_off + BATCH * 4 + bB * 4 + k] = cB;
    }
}

extern "C" void kernel_launch(void* const* d_in, const int* in_sizes, int n_in,
                              void* d_out, int out_size, void* d_ws, size_t ws_size,
                              hipStream_t stream) {
    const float* x  = (const float*)d_in[0];
    const float* Wf = (const float*)d_in[1];
    const float* bf = (const float*)d_in[2];
    const float* tf = (const float*)d_in[3];
    const float* Wi = (const float*)d_in[4];
    const float* bi = (const float*)d_in[5];
    const float* ti = (const float*)d_in[6];
    const float* Wu = (const float*)d_in[7];
    const float* bu = (const float*)d_in[8];
    const float* tu = (const float*)d_in[9];
    const float* Wo = (const float*)d_in[10];
    const float* bo = (const float*)d_in[11];
    const float* to_ = (const float*)d_in[12];
    float* out = (float*)d_out;

    float* Zx = (float*)d_ws;                       // 134.2 MB
    float* Wc = Zx + ZX_FLOATS;                     // 8 KB
    float* bt = Wc + DIM * 16;                      // 64 B

    prep<<<1, 64, 0, stream>>>(Wf, bf, tf, Wi, bi, ti, Wu, bu, tu, Wo, bo, to_, Wc, bt);

    zx_gemm<<<(T_STEPS * BATCH) / 256, 256, 0, stream>>>(
        (const float4*)x, Wc, bt, (float4*)Zx);

    qlstm_rec<<<BATCH / 8, 64, 0, stream>>>(Zx, Wf, Wi, Wu, Wo, out);
}